// Round 8
// baseline (263.523 us; speedup 1.0000x reference)
//
#include <hip/hip_runtime.h>
#include <hip/hip_bf16.h>

#define DIM 384
#define HEADS 6
#define HD 64
#define HIDDEN 1536
#define SEQ 4096
#define BATCH 2
#define NTOK (BATCH*SEQ)   // 8192
#define QKVN (3*DIM)       // 1152

typedef __attribute__((ext_vector_type(4))) float f32x4;
typedef __attribute__((ext_vector_type(16))) float f32x16;
typedef __attribute__((ext_vector_type(8))) short s16x8;
typedef __attribute__((ext_vector_type(4))) unsigned int u32x4;

__device__ __forceinline__ ushort f2bf(float f) {
    union { float f; unsigned u; } v; v.f = f;
    unsigned r = v.u + 0x7FFF + ((v.u >> 16) & 1);
    return (ushort)(r >> 16);
}
__device__ __forceinline__ float bf2f(ushort b) {
    union { unsigned u; float f; } v; v.u = ((unsigned)b) << 16;
    return v.f;
}
__device__ __forceinline__ unsigned cvtpk(float lo, float hi) {
    unsigned r;
    asm("v_cvt_pk_bf16_f32 %0, %1, %2" : "=v"(r) : "v"(lo), "v"(hi));
    return r;
}
__device__ __forceinline__ void pl32swap(unsigned& a, unsigned& b) {
    asm volatile("v_permlane32_swap_b32 %0, %1" : "+v"(a), "+v"(b));
}
__device__ __forceinline__ void g2l(const ushort* g, ushort* s) {
    __builtin_amdgcn_global_load_lds((const __attribute__((address_space(1))) void*)g,
                                     (__attribute__((address_space(3))) void*)s, 16, 0, 0);
}
__device__ __forceinline__ void blockbar() {
    asm volatile("" ::: "memory");
    __builtin_amdgcn_s_barrier();
    asm volatile("" ::: "memory");
}

// ---------------- merged weight f32 -> bf16 ----------------
__global__ void cvt4_kernel(const float4* __restrict__ s0, ushort* __restrict__ d0, int n0,
                            const float4* __restrict__ s1, ushort* __restrict__ d1, int n1,
                            const float4* __restrict__ s2, ushort* __restrict__ d2, int n2,
                            const float4* __restrict__ s3, ushort* __restrict__ d3, int n3) {
    int i = blockIdx.x * 256 + threadIdx.x;
    const float4* s; ushort* d; int k = i;
    if (i < n0) { s = s0; d = d0; }
    else { k -= n0; if (k < n1) { s = s1; d = d1; }
        else { k -= n1; if (k < n2) { s = s2; d = d2; }
            else { k -= n2; if (k >= n3) return; s = s3; d = d3; } } }
    float4 v = s[k];
    ushort4 o; o.x = f2bf(v.x); o.y = f2bf(v.y); o.z = f2bf(v.z); o.w = f2bf(v.w);
    *(ushort4*)(d + (size_t)k * 4) = o;
}

// ---------------- LayerNorm (wave per row, 384 cols) ----------------
__global__ __launch_bounds__(256) void ln_kernel(const float* __restrict__ x,
        const float* __restrict__ w, const float* __restrict__ b,
        ushort* __restrict__ y) {
    int l = threadIdx.x & 63;
    int row = blockIdx.x * 4 + (threadIdx.x >> 6);
    const float* xr = x + (size_t)row * DIM;
    float v[6], s = 0.f, s2 = 0.f;
#pragma unroll
    for (int i = 0; i < 6; ++i) { v[i] = xr[l + 64*i]; s += v[i]; s2 += v[i]*v[i]; }
#pragma unroll
    for (int d = 1; d < 64; d <<= 1) { s += __shfl_xor(s, d); s2 += __shfl_xor(s2, d); }
    float mean = s * (1.f/DIM);
    float var  = s2 * (1.f/DIM) - mean*mean;
    float rstd = rsqrtf(var + 1e-5f);
    ushort* yr = y + (size_t)row * DIM;
#pragma unroll
    for (int i = 0; i < 6; ++i) {
        int c = l + 64*i;
        yr[c] = f2bf((v[i]-mean)*rstd*w[c] + b[c]);
    }
}

// ---------------- GEMM: BMxBN tile, BK step, counted-vmcnt dbuf ----------------
// qkv/fc1: 128x128x64 (32 MFMA/step); proj/fc2: 64x64x128 (16 MFMA/step, 3-12 steps).
// XOR source-side swizzle: stored slot s of row r holds global chunk s^(r&7).
template<int EPI, int BM, int BN, int BK>
__global__ __launch_bounds__(256, 2) void gemm_kernel(
        const ushort* __restrict__ A, const ushort* __restrict__ W,
        const float* __restrict__ bias, const float* __restrict__ resid,
        void* __restrict__ Cout, int M, int N, int K) {
    constexpr int R  = 1024 / (BK*2);   // rows per g2l (8 for BK=64, 4 for BK=128)
    constexpr int L  = 64 / R;          // lanes per row
    constexpr int MI = BM / 32, NI = BN / 32;
    constexpr int KK = BK / 32;
    __shared__ __align__(16) ushort lds_a[2][BM*BK];
    __shared__ __align__(16) ushort lds_w[2][BN*BK];
    const int t = threadIdx.x, l = t & 63, wid = t >> 6;
    const int lo = l & 15, lg = l >> 4, lo7 = lo & 7;
    const int m0 = blockIdx.x * BM, n0 = blockIdx.y * BN;
    const int wm = (wid & 1) * (BM/2), wn = (wid >> 1) * (BN/2);
    f32x4 acc[MI][NI] = {};

    const int srow = l / L;
    const ushort* gA[4]; const ushort* gW[4];
#pragma unroll
    for (int i = 0; i < 4; ++i) {
        int ra = wid*(BM/4) + i*R + srow;
        int rw = wid*(BN/4) + i*R + srow;
        gA[i] = A + (size_t)(m0 + ra) * K + ((l & (L-1)) ^ (ra & 7)) * 8;
        gW[i] = W + (size_t)(n0 + rw) * K + ((l & (L-1)) ^ (rw & 7)) * 8;
    }

#define STAGE(BUF, K0) do {                                                        \
    _Pragma("unroll")                                                              \
    for (int i = 0; i < 4; ++i) g2l(gA[i] + (K0), &lds_a[BUF][(wid*(BM/4)+i*R)*BK]);\
    _Pragma("unroll")                                                              \
    for (int i = 0; i < 4; ++i) g2l(gW[i] + (K0), &lds_w[BUF][(wid*(BN/4)+i*R)*BK]);\
} while (0)
#define WAITC asm volatile("s_waitcnt vmcnt(8)" ::: "memory")
#define WAIT0 asm volatile("s_waitcnt vmcnt(0)" ::: "memory")
#define COMPUTE(BUF) do {                                                          \
    _Pragma("unroll")                                                              \
    for (int kk = 0; kk < KK; ++kk) {                                              \
        const int ch = ((kk*4 + lg) ^ lo7) * 8;                                    \
        s16x8 af[MI], bfr[NI];                                                     \
        _Pragma("unroll")                                                          \
        for (int mi = 0; mi < MI; ++mi)                                            \
            af[mi] = *(const s16x8*)&lds_a[BUF][(wm + mi*16 + lo)*BK + ch];        \
        _Pragma("unroll")                                                          \
        for (int ni = 0; ni < NI; ++ni)                                            \
            bfr[ni] = *(const s16x8*)&lds_w[BUF][(wn + ni*16 + lo)*BK + ch];       \
        _Pragma("unroll")                                                          \
        for (int mi = 0; mi < MI; ++mi)                                            \
            _Pragma("unroll")                                                      \
            for (int ni = 0; ni < NI; ++ni)                                        \
                acc[mi][ni] = __builtin_amdgcn_mfma_f32_16x16x32_bf16(af[mi], bfr[ni], acc[mi][ni], 0,0,0); \
    }                                                                              \
} while (0)

    STAGE(0, 0);
    int k0 = 0, remaining = K / BK;
    while (true) {
        if (remaining > 1) { STAGE(1, k0 + BK); WAITC; } else WAIT0;
        blockbar();
        COMPUTE(0);
        blockbar();
        k0 += BK; if (--remaining == 0) break;
        if (remaining > 1) { STAGE(0, k0 + BK); WAITC; } else WAIT0;
        blockbar();
        COMPUTE(1);
        blockbar();
        k0 += BK; if (--remaining == 0) break;
    }
#undef STAGE
#undef WAITC
#undef WAIT0
#undef COMPUTE

#pragma unroll
    for (int mi = 0; mi < MI; ++mi)
#pragma unroll
    for (int ni = 0; ni < NI; ++ni)
#pragma unroll
    for (int r = 0; r < 4; ++r) {
        int row = m0 + wm + mi*16 + lg*4 + r;
        int col = n0 + wn + ni*16 + lo;
        float c = acc[mi][ni][r];
        size_t idx = (size_t)row * N + col;
        if (EPI == 0) {
            ((ushort*)Cout)[idx] = f2bf(c);
        } else if (EPI == 1) {
            ((float*)Cout)[idx] = c + bias[col] + resid[idx];
        } else if (EPI == 2) {
            c += bias[col];
            ((ushort*)Cout)[idx] = f2bf(0.5f * c * (1.f + erff(c * 0.70710678118f)));
        } else {
            ((float*)Cout)[idx] = 2.f * (c + bias[col]);
        }
    }
}

// ---------------- Flash attention (R6-proven): max-free exp2 softmax, MFMA row-sum ----------------
#define PV_STEP(S, MM, CB) do {                                                   \
    unsigned w0 = cvtpk(S[8*MM+0], S[8*MM+1]);                                    \
    unsigned w1 = cvtpk(S[8*MM+2], S[8*MM+3]);                                    \
    unsigned w2 = cvtpk(S[8*MM+4], S[8*MM+5]);                                    \
    unsigned w3 = cvtpk(S[8*MM+6], S[8*MM+7]);                                    \
    pl32swap(w0, w2); pl32swap(w1, w3);                                           \
    u32x4 fw = {w0, w1, w2, w3};                                                  \
    s16x8 pa = __builtin_bit_cast(s16x8, fw);                                     \
    int colb = ((CB) + G*8) ^ swz0;                                               \
    s16x8 vb0 = *(const s16x8*)&lds_v[half][q31][colb];                           \
    s16x8 vb1 = *(const s16x8*)&lds_v[half][32 + q31][colb ^ 32];                 \
    o0 = __builtin_amdgcn_mfma_f32_32x32x16_bf16(pa, vb0, o0, 0,0,0);             \
    o1 = __builtin_amdgcn_mfma_f32_32x32x16_bf16(pa, vb1, o1, 0,0,0);             \
    ol = __builtin_amdgcn_mfma_f32_32x32x16_bf16(pa, vones, ol, 0,0,0);           \
} while (0)

__global__ __launch_bounds__(256, 3) void attn_kernel(const ushort* __restrict__ qkv,
                                                      ushort* __restrict__ out) {
    __shared__ __align__(16) ushort lds_k[2][64][72];
    __shared__ __align__(16) ushort lds_v[2][64][72];
    const int t = threadIdx.x, l = t & 63, wid = t >> 6;
    const int G = l >> 5, q31 = l & 31, half = wid >> 1;
    const int b = blockIdx.y / HEADS, h = blockIdx.y % HEADS;
    const ushort* base = qkv + (size_t)b * SEQ * QKVN + h * HD;
    const int q0 = blockIdx.x * 64 + (wid & 1) * 32;

    // Q fragments pre-scaled by 0.125*log2(e) (exp2 domain)
    const float QSC = 0.1803368801111137f;
    s16x8 qf[4];
#pragma unroll
    for (int dc = 0; dc < 4; ++dc) {
        s16x8 qv = *(const s16x8*)(base + (size_t)(q0 + q31) * QKVN + dc*16 + G*8);
#pragma unroll
        for (int j = 0; j < 8; ++j)
            qv[j] = (short)f2bf(bf2f((ushort)qv[j]) * QSC);
        qf[dc] = qv;
    }
    s16x8 vones;
#pragma unroll
    for (int j = 0; j < 8; ++j) vones[j] = (short)0x3F80;   // bf16 1.0

    f32x16 o0 = {}, o1 = {}, ol = {};

    const int u = t & 127, sa = u >> 3, sc = u & 7;
    const ushort* kbase = base + DIM;
    const ushort* vbase = base + 2*DIM;
    const int key0base = half * (SEQ/2);
    const int swz0 = ((q31 >> 3) & 3) << 3;

    s16x8 kreg[4], vreg[4];
#pragma unroll
    for (int p = 0; p < 4; ++p) {
        kreg[p] = *(const s16x8*)(kbase + (size_t)(key0base + p*16 + sa) * QKVN + sc*8);
        vreg[p] = *(const s16x8*)(vbase + (size_t)(key0base + p*16 + sa) * QKVN + sc*8);
    }

    for (int it = 0; it < 32; ++it) {
        const int key0 = key0base + it*64;
        __syncthreads();   // previous compute done; LDS writable
#pragma unroll
        for (int p = 0; p < 4; ++p) {
            *(s16x8*)&lds_k[half][p*16 + sa][sc*8] = kreg[p];
            const int colp = (p*16 + sa) ^ ((sc & 3) << 3) ^ ((sc >> 2) << 5);
#pragma unroll
            for (int j = 0; j < 8; ++j)
                lds_v[half][sc*8 + j][colp] = (ushort)vreg[p][j];
        }
        __syncthreads();
        if (it < 31) {     // prefetch next K+V tiles into regs
#pragma unroll
            for (int p = 0; p < 4; ++p) {
                kreg[p] = *(const s16x8*)(kbase + (size_t)(key0 + 64 + p*16 + sa) * QKVN + sc*8);
                vreg[p] = *(const s16x8*)(vbase + (size_t)(key0 + 64 + p*16 + sa) * QKVN + sc*8);
            }
        }

        // S^T = K * Q^T
        f32x16 st0 = {}, st1 = {};
        __builtin_amdgcn_s_setprio(1);
#pragma unroll
        for (int dc = 0; dc < 4; ++dc) {
            s16x8 kf0 = *(const s16x8*)&lds_k[half][q31][dc*16 + G*8];
            s16x8 kf1 = *(const s16x8*)&lds_k[half][32 + q31][dc*16 + G*8];
            st0 = __builtin_amdgcn_mfma_f32_32x32x16_bf16(kf0, qf[dc], st0, 0,0,0);
            st1 = __builtin_amdgcn_mfma_f32_32x32x16_bf16(kf1, qf[dc], st1, 0,0,0);
        }
        __builtin_amdgcn_s_setprio(0);

        // max-free exp2 (LN-bounded; f32 cannot overflow); sum comes from ones-MFMA
#pragma unroll
        for (int r = 0; r < 16; ++r) {
            st0[r] = exp2f(st0[r]);
            st1[r] = exp2f(st1[r]);
        }

        __builtin_amdgcn_s_setprio(1);
        PV_STEP(st0, 0, 0);
        PV_STEP(st0, 1, 16);
        PV_STEP(st1, 0, 32);
        PV_STEP(st1, 1, 48);
        __builtin_amdgcn_s_setprio(0);
    }

    // merge kv-halves (plain add) and write; l per row r direct from ol
    __syncthreads();
    float* mb = (float*)&lds_k[0][0][0];   // 16 KB: [pair*2+dt][r][lane]
    float* ml = (float*)&lds_v[0][0][0];   // 8 KB:  [pair][r][lane]
    if (half == 1) {
#pragma unroll
        for (int r = 0; r < 16; ++r) {
            mb[((wid&1)*2 + 0)*1024 + r*64 + l] = o0[r];
            mb[((wid&1)*2 + 1)*1024 + r*64 + l] = o1[r];
            ml[(wid&1)*1024 + r*64 + l] = ol[r];
        }
    }
    __syncthreads();
    if (half == 0) {
        ushort* ob = out + (size_t)b * SEQ * DIM + h * HD;
#pragma unroll
        for (int r = 0; r < 16; ++r) {
            float invr = 1.0f / (ol[r] + ml[(wid&1)*1024 + r*64 + l]);
            float v0 = (o0[r] + mb[((wid&1)*2 + 0)*1024 + r*64 + l]) * invr;
            float v1 = (o1[r] + mb[((wid&1)*2 + 1)*1024 + r*64 + l]) * invr;
            int qr = (r & 3) + 8*(r >> 2) + 4*G;
            int row = q0 + qr;
            ob[(size_t)row * DIM + q31]      = f2bf(v0);
            ob[(size_t)row * DIM + 32 + q31] = f2bf(v1);
        }
    }
}

extern "C" void kernel_launch(void* const* d_in, const int* in_sizes, int n_in,
                              void* d_out, int out_size, void* d_ws, size_t ws_size,
                              hipStream_t stream) {
    const float* x      = (const float*)d_in[0];
    const float* qkv_w  = (const float*)d_in[1];
    const float* proj_w = (const float*)d_in[2];
    const float* proj_b = (const float*)d_in[3];
    const float* ln1_w  = (const float*)d_in[4];
    const float* ln1_b  = (const float*)d_in[5];
    const float* ln2_w  = (const float*)d_in[6];
    const float* ln2_b  = (const float*)d_in[7];
    const float* fc1_w  = (const float*)d_in[8];
    const float* fc1_b  = (const float*)d_in[9];
    const float* fc2_w  = (const float*)d_in[10];
    const float* fc2_b  = (const float*)d_in[11];
    float* outp = (float*)d_out;

    char* ws = (char*)d_ws;
    size_t off = 0;
    auto alloc = [&](size_t bytes) {
        off = (off + 255) & ~(size_t)255;
        void* p = ws + off;
        off += bytes;
        return p;
    };
    ushort* wq   = (ushort*)alloc((size_t)QKVN * DIM * 2);
    ushort* wp   = (ushort*)alloc((size_t)DIM * DIM * 2);
    ushort* w1   = (ushort*)alloc((size_t)HIDDEN * DIM * 2);
    ushort* w2   = (ushort*)alloc((size_t)DIM * HIDDEN * 2);
    ushort* y1   = (ushort*)alloc((size_t)NTOK * DIM * 2);
    ushort* qkvb = (ushort*)alloc((size_t)NTOK * QKVN * 2);
    ushort* ao   = (ushort*)alloc((size_t)NTOK * DIM * 2);
    float*  res  = (float*) alloc((size_t)NTOK * DIM * 4);
    ushort* y2   = (ushort*)alloc((size_t)NTOK * DIM * 2);
    ushort* hb   = (ushort*)alloc((size_t)NTOK * HIDDEN * 2);

    const int n0 = QKVN*DIM/4, n1 = DIM*DIM/4, n2 = HIDDEN*DIM/4, n3 = DIM*HIDDEN/4;
    cvt4_kernel<<<(n0+n1+n2+n3 + 255)/256, 256, 0, stream>>>(
        (const float4*)qkv_w, wq, n0, (const float4*)proj_w, wp, n1,
        (const float4*)fc1_w, w1, n2, (const float4*)fc2_w, w2, n3);

    ln_kernel<<<NTOK/4, 256, 0, stream>>>(x, ln1_w, ln1_b, y1);
    gemm_kernel<0,128,128,64><<<dim3(NTOK/128, QKVN/128), 256, 0, stream>>>(y1, wq, nullptr, nullptr, qkvb, NTOK, QKVN, DIM);
    attn_kernel<<<dim3(SEQ/64, BATCH*HEADS), 256, 0, stream>>>(qkvb, ao);
    gemm_kernel<1,64,64,128><<<dim3(NTOK/64, DIM/64), 256, 0, stream>>>(ao, wp, proj_b, x, res, NTOK, DIM, DIM);
    ln_kernel<<<NTOK/4, 256, 0, stream>>>(res, ln2_w, ln2_b, y2);
    gemm_kernel<2,128,128,64><<<dim3(NTOK/128, HIDDEN/128), 256, 0, stream>>>(y2, w1, fc1_b, nullptr, hb, NTOK, HIDDEN, DIM);
    gemm_kernel<3,64,64,128><<<dim3(NTOK/64, DIM/64), 256, 0, stream>>>(hb, w2, fc2_b, nullptr, outp, NTOK, DIM, HIDDEN);
}

// Round 9
// 245.887 us; speedup vs baseline: 1.0717x; 1.0717x over previous
//
#include <hip/hip_runtime.h>
#include <hip/hip_bf16.h>

#define DIM 384
#define HEADS 6
#define HD 64
#define HIDDEN 1536
#define SEQ 4096
#define BATCH 2
#define NTOK (BATCH*SEQ)   // 8192
#define QKVN (3*DIM)       // 1152

typedef __attribute__((ext_vector_type(4))) float f32x4;
typedef __attribute__((ext_vector_type(16))) float f32x16;
typedef __attribute__((ext_vector_type(8))) short s16x8;
typedef __attribute__((ext_vector_type(4))) unsigned int u32x4;

__device__ __forceinline__ ushort f2bf(float f) {
    union { float f; unsigned u; } v; v.f = f;
    unsigned r = v.u + 0x7FFF + ((v.u >> 16) & 1);
    return (ushort)(r >> 16);
}
__device__ __forceinline__ float bf2f(ushort b) {
    union { unsigned u; float f; } v; v.u = ((unsigned)b) << 16;
    return v.f;
}
__device__ __forceinline__ unsigned cvtpk(float lo, float hi) {
    unsigned r;
    asm("v_cvt_pk_bf16_f32 %0, %1, %2" : "=v"(r) : "v"(lo), "v"(hi));
    return r;
}
__device__ __forceinline__ void pl32swap(unsigned& a, unsigned& b) {
    asm volatile("v_permlane32_swap_b32 %0, %1" : "+v"(a), "+v"(b));
}
__device__ __forceinline__ void g2l(const ushort* g, ushort* s) {
    __builtin_amdgcn_global_load_lds((const __attribute__((address_space(1))) void*)g,
                                     (__attribute__((address_space(3))) void*)s, 16, 0, 0);
}
__device__ __forceinline__ void blockbar() {
    asm volatile("" ::: "memory");
    __builtin_amdgcn_s_barrier();
    asm volatile("" ::: "memory");
}

// ---------------- prep: weight cvt (4 mats) + LN1, fused ----------------
__global__ __launch_bounds__(256) void prep_kernel(
        const float4* __restrict__ s0, ushort* __restrict__ d0, int n0,
        const float4* __restrict__ s1, ushort* __restrict__ d1, int n1,
        const float4* __restrict__ s2, ushort* __restrict__ d2, int n2,
        const float4* __restrict__ s3, ushort* __restrict__ d3, int n3,
        int ncvt,
        const float* __restrict__ x, const float* __restrict__ lw,
        const float* __restrict__ lb, ushort* __restrict__ y) {
    const int bx = blockIdx.x, t = threadIdx.x;
    if (bx < ncvt) {
        int i = bx * 256 + t;
        const float4* s; ushort* d; int k = i;
        if (i < n0) { s = s0; d = d0; }
        else { k -= n0; if (k < n1) { s = s1; d = d1; }
            else { k -= n1; if (k < n2) { s = s2; d = d2; }
                else { k -= n2; if (k >= n3) return; s = s3; d = d3; } } }
        float4 v = s[k];
        ushort4 o; o.x = f2bf(v.x); o.y = f2bf(v.y); o.z = f2bf(v.z); o.w = f2bf(v.w);
        *(ushort4*)(d + (size_t)k * 4) = o;
    } else {
        int l = t & 63;
        int row = (bx - ncvt) * 4 + (t >> 6);
        const float* xr = x + (size_t)row * DIM;
        float v[6], s = 0.f, s2 = 0.f;
#pragma unroll
        for (int i = 0; i < 6; ++i) { v[i] = xr[l + 64*i]; s += v[i]; s2 += v[i]*v[i]; }
#pragma unroll
        for (int d = 1; d < 64; d <<= 1) { s += __shfl_xor(s, d); s2 += __shfl_xor(s2, d); }
        float mean = s * (1.f/DIM);
        float var  = s2 * (1.f/DIM) - mean*mean;
        float rstd = rsqrtf(var + 1e-5f);
        ushort* yr = y + (size_t)row * DIM;
#pragma unroll
        for (int i = 0; i < 6; ++i) {
            int c = l + 64*i;
            yr[c] = f2bf((v[i]-mean)*rstd*lw[c] + lb[c]);
        }
    }
}

// ---------------- LayerNorm (wave per row, 384 cols) ----------------
__global__ __launch_bounds__(256) void ln_kernel(const float* __restrict__ x,
        const float* __restrict__ w, const float* __restrict__ b,
        ushort* __restrict__ y) {
    int l = threadIdx.x & 63;
    int row = blockIdx.x * 4 + (threadIdx.x >> 6);
    const float* xr = x + (size_t)row * DIM;
    float v[6], s = 0.f, s2 = 0.f;
#pragma unroll
    for (int i = 0; i < 6; ++i) { v[i] = xr[l + 64*i]; s += v[i]; s2 += v[i]*v[i]; }
#pragma unroll
    for (int d = 1; d < 64; d <<= 1) { s += __shfl_xor(s, d); s2 += __shfl_xor(s2, d); }
    float mean = s * (1.f/DIM);
    float var  = s2 * (1.f/DIM) - mean*mean;
    float rstd = rsqrtf(var + 1e-5f);
    ushort* yr = y + (size_t)row * DIM;
#pragma unroll
    for (int i = 0; i < 6; ++i) {
        int c = l + 64*i;
        yr[c] = f2bf((v[i]-mean)*rstd*w[c] + b[c]);
    }
}

// ---------------- V transpose: qkvb V-cols -> vt[b*H+h][d][SEQ] ----------------
__global__ __launch_bounds__(256) void vtrans_kernel(const ushort* __restrict__ qkvb,
                                                     ushort* __restrict__ vt) {
    __shared__ __align__(16) ushort lds[64][72];
    const int t = threadIdx.x;
    const int key0 = blockIdx.x * 64;
    const int bh = blockIdx.y;
    const int b = bh / HEADS, h = bh % HEADS;
    const ushort* src = qkvb + (size_t)b * SEQ * QKVN + 2*DIM + h*HD;
    const int ky = t >> 3, c = t & 7;
#pragma unroll
    for (int hf = 0; hf < 2; ++hf) {
        s16x8 v = *(const s16x8*)(src + (size_t)(key0 + hf*32 + ky) * QKVN + c*8);
        *(s16x8*)&lds[hf*32 + ky][c*8] = v;
    }
    __syncthreads();
    ushort* dst = vt + (size_t)bh * 64 * SEQ + key0;
#pragma unroll
    for (int hf = 0; hf < 2; ++hf) {
        const int d = hf*32 + (t >> 3), kc = t & 7;
        s16x8 o;
#pragma unroll
        for (int j = 0; j < 8; ++j) o[j] = (short)lds[kc*8 + j][d];
        *(s16x8*)(dst + (size_t)d * SEQ + kc*8) = o;
    }
}

// ---------------- GEMM (R6-proven): 64xBN tile, BK=64, counted-vmcnt dbuf ----------------
template<int EPI, int BN>
__global__ __launch_bounds__(256, (BN == 128 ? 3 : 4)) void gemm_kernel(
        const ushort* __restrict__ A, const ushort* __restrict__ W,
        const float* __restrict__ bias, const float* __restrict__ resid,
        void* __restrict__ Cout, int M, int N, int K) {
    __shared__ __align__(16) ushort lds_a[2][64*64];
    __shared__ __align__(16) ushort lds_w[2][BN*64];
    const int t = threadIdx.x, l = t & 63, wid = t >> 6;
    const int lo = l & 15, lg = l >> 4;
    const int m0 = blockIdx.x * 64, n0 = blockIdx.y * BN;
    constexpr int NI = BN / 32;
    constexpr int WW = BN / 32;
    const int wm = (wid & 1) * 32, wn = (wid >> 1) * (BN / 2);
    f32x4 acc[2][NI] = {};

    const int srow8 = l >> 3;
    const int schunk = (l & 7) ^ srow8;
    const ushort* gA[2];
#pragma unroll
    for (int w = 0; w < 2; ++w)
        gA[w] = A + (size_t)(m0 + wid*16 + w*8 + srow8) * K + schunk*8;
    const ushort* gW[WW];
#pragma unroll
    for (int w = 0; w < WW; ++w)
        gW[w] = W + (size_t)(n0 + wid*(8*WW) + w*8 + srow8) * K + schunk*8;

#define STAGE(BUF, K0) do {                                                    \
    _Pragma("unroll")                                                          \
    for (int w = 0; w < 2; ++w)  g2l(gA[w] + (K0), &lds_a[BUF][(wid*16 + w*8)*64]); \
    _Pragma("unroll")                                                          \
    for (int w = 0; w < WW; ++w) g2l(gW[w] + (K0), &lds_w[BUF][(wid*(8*WW) + w*8)*64]); \
} while (0)

#define WAITC do {                                                             \
    if constexpr (BN == 128) asm volatile("s_waitcnt vmcnt(6)" ::: "memory");  \
    else                     asm volatile("s_waitcnt vmcnt(4)" ::: "memory");  \
} while (0)
#define WAIT0 asm volatile("s_waitcnt vmcnt(0)" ::: "memory")

    const int lo7 = lo & 7;
#define COMPUTE(BUF) do {                                                      \
    _Pragma("unroll")                                                          \
    for (int kk = 0; kk < 2; ++kk) {                                           \
        const int ch = ((kk*4 + lg) ^ lo7) * 8;                                \
        s16x8 af[2], bfr[NI];                                                  \
        _Pragma("unroll")                                                      \
        for (int mi = 0; mi < 2; ++mi)                                         \
            af[mi] = *(const s16x8*)&lds_a[BUF][(wm + mi*16 + lo)*64 + ch];    \
        _Pragma("unroll")                                                      \
        for (int ni = 0; ni < NI; ++ni)                                        \
            bfr[ni] = *(const s16x8*)&lds_w[BUF][(wn + ni*16 + lo)*64 + ch];   \
        _Pragma("unroll")                                                      \
        for (int mi = 0; mi < 2; ++mi)                                         \
            _Pragma("unroll")                                                  \
            for (int ni = 0; ni < NI; ++ni)                                    \
                acc[mi][ni] = __builtin_amdgcn_mfma_f32_16x16x32_bf16(af[mi], bfr[ni], acc[mi][ni], 0,0,0); \
    }                                                                          \
} while (0)

    STAGE(0, 0);
    int k0 = 0, remaining = K / 64;
    while (true) {
        if (remaining > 1) { STAGE(1, k0 + 64); WAITC; } else WAIT0;
        blockbar();
        COMPUTE(0);
        blockbar();
        k0 += 64; if (--remaining == 0) break;
        if (remaining > 1) { STAGE(0, k0 + 64); WAITC; } else WAIT0;
        blockbar();
        COMPUTE(1);
        blockbar();
        k0 += 64; if (--remaining == 0) break;
    }
#undef STAGE
#undef WAITC
#undef WAIT0
#undef COMPUTE

#pragma unroll
    for (int mi = 0; mi < 2; ++mi)
#pragma unroll
    for (int ni = 0; ni < NI; ++ni)
#pragma unroll
    for (int r = 0; r < 4; ++r) {
        int row = m0 + wm + mi*16 + lg*4 + r;
        int col = n0 + wn + ni*16 + lo;
        float c = acc[mi][ni][r];
        size_t idx = (size_t)row * N + col;
        if (EPI == 0) {
            ((ushort*)Cout)[idx] = f2bf(c);
        } else if (EPI == 1) {
            ((float*)Cout)[idx] = c + bias[col] + resid[idx];
        } else if (EPI == 2) {
            c += bias[col];
            ((ushort*)Cout)[idx] = f2bf(0.5f * c * (1.f + erff(c * 0.70710678118f)));
        } else {
            ((float*)Cout)[idx] = 2.f * (c + bias[col]);
        }
    }
}

// ---------------- Flash attention: pre-transposed V, vector staging only ----------------
// lds_v[half][d][key] (stride 72). Write: lane (sa=u>>3, sc=u&7) stores d=sa+p*16,
// keys sc*8..+7 -> b128, banks 4((d&7)+sc) even. Read vb0/vb1: rows d=l&31 / 32+,
// col CB+G*8: banks 4(row+chunk) mod 32, 4-even. No swizzle needed (pad-72 spreads rows).
#define PV_STEP(S, MM, CB) do {                                                   \
    unsigned w0 = cvtpk(S[8*MM+0], S[8*MM+1]);                                    \
    unsigned w1 = cvtpk(S[8*MM+2], S[8*MM+3]);                                    \
    unsigned w2 = cvtpk(S[8*MM+4], S[8*MM+5]);                                    \
    unsigned w3 = cvtpk(S[8*MM+6], S[8*MM+7]);                                    \
    pl32swap(w0, w2); pl32swap(w1, w3);                                           \
    u32x4 fw = {w0, w1, w2, w3};                                                  \
    s16x8 pa = __builtin_bit_cast(s16x8, fw);                                     \
    int colb = (CB) + G*8;                                                        \
    s16x8 vb0 = *(const s16x8*)&lds_v[half][q31][colb];                           \
    s16x8 vb1 = *(const s16x8*)&lds_v[half][32 + q31][colb];                      \
    o0 = __builtin_amdgcn_mfma_f32_32x32x16_bf16(pa, vb0, o0, 0,0,0);             \
    o1 = __builtin_amdgcn_mfma_f32_32x32x16_bf16(pa, vb1, o1, 0,0,0);             \
    ol = __builtin_amdgcn_mfma_f32_32x32x16_bf16(pa, vones, ol, 0,0,0);           \
} while (0)

__global__ __launch_bounds__(256, 3) void attn_kernel(const ushort* __restrict__ qkv,
                                                      const ushort* __restrict__ vt,
                                                      ushort* __restrict__ out) {
    __shared__ __align__(16) ushort lds_k[2][64][72];
    __shared__ __align__(16) ushort lds_v[2][64][72];
    const int t = threadIdx.x, l = t & 63, wid = t >> 6;
    const int G = l >> 5, q31 = l & 31, half = wid >> 1;
    const int b = blockIdx.y / HEADS, h = blockIdx.y % HEADS;
    const ushort* base = qkv + (size_t)b * SEQ * QKVN + h * HD;
    const ushort* vtb = vt + (size_t)blockIdx.y * 64 * SEQ;
    const int q0 = blockIdx.x * 64 + (wid & 1) * 32;

    // Q fragments pre-scaled by 0.125*log2(e) (exp2 domain)
    const float QSC = 0.1803368801111137f;
    s16x8 qf[4];
#pragma unroll
    for (int dc = 0; dc < 4; ++dc) {
        s16x8 qv = *(const s16x8*)(base + (size_t)(q0 + q31) * QKVN + dc*16 + G*8);
#pragma unroll
        for (int j = 0; j < 8; ++j)
            qv[j] = (short)f2bf(bf2f((ushort)qv[j]) * QSC);
        qf[dc] = qv;
    }
    s16x8 vones;
#pragma unroll
    for (int j = 0; j < 8; ++j) vones[j] = (short)0x3F80;   // bf16 1.0

    f32x16 o0 = {}, o1 = {}, ol = {};

    const int u = t & 127, sa = u >> 3, sc = u & 7;   // sa 0..15, sc 0..7
    const ushort* kbase = base + DIM;
    const int key0base = half * (SEQ/2);

    s16x8 kreg[4], vreg[4];
#pragma unroll
    for (int p = 0; p < 4; ++p) {
        kreg[p] = *(const s16x8*)(kbase + (size_t)(key0base + p*16 + sa) * QKVN + sc*8);
        vreg[p] = *(const s16x8*)(vtb + (size_t)(sa + p*16) * SEQ + key0base + sc*8);
    }

    for (int it = 0; it < 32; ++it) {
        const int key0 = key0base + it*64;
        __syncthreads();   // previous compute done; LDS writable
#pragma unroll
        for (int p = 0; p < 4; ++p) {
            *(s16x8*)&lds_k[half][p*16 + sa][sc*8] = kreg[p];
            *(s16x8*)&lds_v[half][sa + p*16][sc*8] = vreg[p];
        }
        __syncthreads();
        if (it < 31) {     // prefetch next K + V^T tiles into regs (T14)
#pragma unroll
            for (int p = 0; p < 4; ++p) {
                kreg[p] = *(const s16x8*)(kbase + (size_t)(key0 + 64 + p*16 + sa) * QKVN + sc*8);
                vreg[p] = *(const s16x8*)(vtb + (size_t)(sa + p*16) * SEQ + key0 + 64 + sc*8);
            }
        }

        // S^T = K * Q^T : lane holds 32 keys for its q = l&31
        f32x16 st0 = {}, st1 = {};
        __builtin_amdgcn_s_setprio(1);
#pragma unroll
        for (int dc = 0; dc < 4; ++dc) {
            s16x8 kf0 = *(const s16x8*)&lds_k[half][q31][dc*16 + G*8];
            s16x8 kf1 = *(const s16x8*)&lds_k[half][32 + q31][dc*16 + G*8];
            st0 = __builtin_amdgcn_mfma_f32_32x32x16_bf16(kf0, qf[dc], st0, 0,0,0);
            st1 = __builtin_amdgcn_mfma_f32_32x32x16_bf16(kf1, qf[dc], st1, 0,0,0);
        }
        __builtin_amdgcn_s_setprio(0);

        // max-free exp2 (LN-bounded; f32 cannot overflow); row-sum via ones-MFMA
#pragma unroll
        for (int r = 0; r < 16; ++r) {
            st0[r] = exp2f(st0[r]);
            st1[r] = exp2f(st1[r]);
        }

        __builtin_amdgcn_s_setprio(1);
        PV_STEP(st0, 0, 0);
        PV_STEP(st0, 1, 16);
        PV_STEP(st1, 0, 32);
        PV_STEP(st1, 1, 48);
        __builtin_amdgcn_s_setprio(0);
    }

    // merge kv-halves (plain add) and write; l per row direct from ol
    __syncthreads();
    float* mb = (float*)&lds_k[0][0][0];   // 16 KB: [pair*2+dt][r][lane]
    float* ml = (float*)&lds_v[0][0][0];   // 8 KB:  [pair][r][lane]
    if (half == 1) {
#pragma unroll
        for (int r = 0; r < 16; ++r) {
            mb[((wid&1)*2 + 0)*1024 + r*64 + l] = o0[r];
            mb[((wid&1)*2 + 1)*1024 + r*64 + l] = o1[r];
            ml[(wid&1)*1024 + r*64 + l] = ol[r];
        }
    }
    __syncthreads();
    if (half == 0) {
        ushort* ob = out + (size_t)b * SEQ * DIM + h * HD;
#pragma unroll
        for (int r = 0; r < 16; ++r) {
            float invr = 1.0f / (ol[r] + ml[(wid&1)*1024 + r*64 + l]);
            float v0 = (o0[r] + mb[((wid&1)*2 + 0)*1024 + r*64 + l]) * invr;
            float v1 = (o1[r] + mb[((wid&1)*2 + 1)*1024 + r*64 + l]) * invr;
            int qr = (r & 3) + 8*(r >> 2) + 4*G;
            int row = q0 + qr;
            ob[(size_t)row * DIM + q31]      = f2bf(v0);
            ob[(size_t)row * DIM + 32 + q31] = f2bf(v1);
        }
    }
}

extern "C" void kernel_launch(void* const* d_in, const int* in_sizes, int n_in,
                              void* d_out, int out_size, void* d_ws, size_t ws_size,
                              hipStream_t stream) {
    const float* x      = (const float*)d_in[0];
    const float* qkv_w  = (const float*)d_in[1];
    const float* proj_w = (const float*)d_in[2];
    const float* proj_b = (const float*)d_in[3];
    const float* ln1_w  = (const float*)d_in[4];
    const float* ln1_b  = (const float*)d_in[5];
    const float* ln2_w  = (const float*)d_in[6];
    const float* ln2_b  = (const float*)d_in[7];
    const float* fc1_w  = (const float*)d_in[8];
    const float* fc1_b  = (const float*)d_in[9];
    const float* fc2_w  = (const float*)d_in[10];
    const float* fc2_b  = (const float*)d_in[11];
    float* outp = (float*)d_out;

    char* ws = (char*)d_ws;
    size_t off = 0;
    auto alloc = [&](size_t bytes) {
        off = (off + 255) & ~(size_t)255;
        void* p = ws + off;
        off += bytes;
        return p;
    };
    ushort* wq   = (ushort*)alloc((size_t)QKVN * DIM * 2);
    ushort* wp   = (ushort*)alloc((size_t)DIM * DIM * 2);
    ushort* w1   = (ushort*)alloc((size_t)HIDDEN * DIM * 2);
    ushort* w2   = (ushort*)alloc((size_t)DIM * HIDDEN * 2);
    ushort* y1   = (ushort*)alloc((size_t)NTOK * DIM * 2);
    ushort* qkvb = (ushort*)alloc((size_t)NTOK * QKVN * 2);
    ushort* vtb  = (ushort*)alloc((size_t)BATCH * HEADS * HD * SEQ * 2);
    ushort* ao   = (ushort*)alloc((size_t)NTOK * DIM * 2);
    float*  res  = (float*) alloc((size_t)NTOK * DIM * 4);
    ushort* y2   = (ushort*)alloc((size_t)NTOK * DIM * 2);
    ushort* hb   = (ushort*)alloc((size_t)NTOK * HIDDEN * 2);

    const int n0 = QKVN*DIM/4, n1 = DIM*DIM/4, n2 = HIDDEN*DIM/4, n3 = DIM*HIDDEN/4;
    const int ncvt = (n0+n1+n2+n3 + 255)/256;
    prep_kernel<<<ncvt + NTOK/4, 256, 0, stream>>>(
        (const float4*)qkv_w, wq, n0, (const float4*)proj_w, wp, n1,
        (const float4*)fc1_w, w1, n2, (const float4*)fc2_w, w2, n3,
        ncvt, x, ln1_w, ln1_b, y1);

    gemm_kernel<0,128><<<dim3(NTOK/64, QKVN/128), 256, 0, stream>>>(y1, wq, nullptr, nullptr, qkvb, NTOK, QKVN, DIM);
    vtrans_kernel<<<dim3(SEQ/64, BATCH*HEADS), 256, 0, stream>>>(qkvb, vtb);
    attn_kernel<<<dim3(SEQ/64, BATCH*HEADS), 256, 0, stream>>>(qkvb, vtb, ao);
    gemm_kernel<1,64><<<dim3(NTOK/64, DIM/64), 256, 0, stream>>>(ao, wp, proj_b, x, res, NTOK, DIM, DIM);
    ln_kernel<<<NTOK/4, 256, 0, stream>>>(res, ln2_w, ln2_b, y2);
    gemm_kernel<2,128><<<dim3(NTOK/64, HIDDEN/128), 256, 0, stream>>>(y2, w1, fc1_b, nullptr, hb, NTOK, HIDDEN, DIM);
    gemm_kernel<3,64><<<dim3(NTOK/64, DIM/64), 256, 0, stream>>>(hb, w2, fc2_b, nullptr, outp, NTOK, DIM, HIDDEN);
}